// Round 3
// baseline (311.792 us; speedup 1.0000x reference)
//
#include <hip/hip_runtime.h>

// ---------------------------------------------------------------------------
// MLA (LoraQKV) pipeline for MI355X, bf16 MFMA everywhere.
//   1) cvt_pad converts; 2) gemm C1 = hs@W1^T; 3) rmsnorm_rope;
//   4) gemm Qf/KVf; 5) q_post/kv_post; 6) flash_attn; 7) gemm out = Ao@o_w^T.
// R3: 8-wave double-buffered 2-phase GEMM (BN templated 64/128, 2 blocks/CU);
//     8-wave double-buffered flash (128 q-rows/block, 1 barrier/tile,
//     exp2-domain softmax with log2e folded into Q scale, defer-max THR=8).
// ---------------------------------------------------------------------------

typedef __attribute__((ext_vector_type(8))) __bf16 bf16x8;
typedef __attribute__((ext_vector_type(4))) float f32x4;

__device__ __forceinline__ unsigned short f2bf(float f) {
  unsigned int x = __builtin_bit_cast(unsigned int, f);
  x += 0x7fffu + ((x >> 16) & 1u);
  return (unsigned short)(x >> 16);
}
__device__ __forceinline__ void gload_lds16(const void* g, void* l) {
  __builtin_amdgcn_global_load_lds(
      (const __attribute__((address_space(1))) void*)g,
      (__attribute__((address_space(3))) void*)l, 16, 0, 0);
}

// ---------------- converts ----------------
__global__ __launch_bounds__(256) void cvt_pad(const float* __restrict__ src,
                                               unsigned short* __restrict__ dst,
                                               size_t n_src, size_t n_tot) {
  size_t i = ((size_t)blockIdx.x * 256 + threadIdx.x) * 4;
  if (i >= n_tot) return;
  unsigned short o0 = 0, o1 = 0, o2 = 0, o3 = 0;
  if (i < n_src) {
    float4 v = *reinterpret_cast<const float4*>(src + i);
    o0 = f2bf(v.x); o1 = f2bf(v.y); o2 = f2bf(v.z); o3 = f2bf(v.w);
  }
  *reinterpret_cast<ushort4*>(dst + i) = make_ushort4(o0, o1, o2, o3);
}

// ---------------- GEMM: C[M,N] = A[M,K] @ B[N,K]^T (bf16 in, f32 out) -------
// 128xBN tile, BK=64, 512 threads (8 waves), double-buffered LDS, 2-phase:
// stage(t+1) issued before compute(t); one barrier (w/ vmcnt drain) per K-step.
template <int BN>
__global__ __launch_bounds__(512, 4) void gemm_bt2(const unsigned short* __restrict__ A,
                                                   const unsigned short* __restrict__ B,
                                                   float* __restrict__ C,
                                                   int M, int N, int K) {
  constexpr int WC   = (BN == 128) ? 4 : 2;   // waves along N
  constexpr int WTM  = (BN == 128) ? 64 : 32; // wave tile rows
  constexpr int MF_M = WTM / 16;
  __shared__ unsigned short lA0[128 * 64], lA1[128 * 64];
  __shared__ unsigned short lB0[BN * 64], lB1[BN * 64];
  const int tid = threadIdx.x, lane = tid & 63, wv = tid >> 6;
  const int wr = wv / WC, wc = wv % WC;
  const int bm = blockIdx.y * 128, bn = blockIdx.x * BN;

  f32x4 acc[MF_M][2] = {};

  const int ar0 = tid >> 3;          // chunk row base (c = i*512 + tid, row = c>>3)
  const int acol = (tid & 7) * 8;

  auto stage = [&](unsigned short* la, unsigned short* lb, int k0) {
#pragma unroll
    for (int i = 0; i < 2; ++i)
      gload_lds16(A + (size_t)(bm + i * 64 + ar0) * K + k0 + acol,
                  &la[(i * 512 + wv * 64) * 8]);
    if constexpr (BN == 128) {
#pragma unroll
      for (int i = 0; i < 2; ++i)
        gload_lds16(B + (size_t)(bn + i * 64 + ar0) * K + k0 + acol,
                    &lb[(i * 512 + wv * 64) * 8]);
    } else {
      gload_lds16(B + (size_t)(bn + ar0) * K + k0 + acol, &lb[(wv * 64) * 8]);
    }
  };

  auto compute = [&](const unsigned short* la, const unsigned short* lb) {
#pragma unroll
    for (int ks = 0; ks < 2; ++ks) {
      bf16x8 af[MF_M], bfr[2];
#pragma unroll
      for (int m = 0; m < MF_M; ++m)
        af[m] = *reinterpret_cast<const bf16x8*>(
            &la[(wr * WTM + m * 16 + (lane & 15)) * 64 + ks * 32 + (lane >> 4) * 8]);
#pragma unroll
      for (int n = 0; n < 2; ++n)
        bfr[n] = *reinterpret_cast<const bf16x8*>(
            &lb[(wc * 32 + n * 16 + (lane & 15)) * 64 + ks * 32 + (lane >> 4) * 8]);
#pragma unroll
      for (int m = 0; m < MF_M; ++m)
#pragma unroll
        for (int n = 0; n < 2; ++n)
          acc[m][n] = __builtin_amdgcn_mfma_f32_16x16x32_bf16(af[m], bfr[n], acc[m][n], 0, 0, 0);
    }
  };

  stage(lA0, lB0, 0);
  for (int k0 = 0; k0 < K; k0 += 128) {   // K % 128 == 0 for all call sites
    __syncthreads();                      // drain stage(k0) for buf0
    stage(lA1, lB1, k0 + 64);             // in flight during compute(buf0)
    compute(lA0, lB0);
    __syncthreads();                      // drain stage(k0+64); buf0 free
    if (k0 + 128 < K) stage(lA0, lB0, k0 + 128);
    compute(lA1, lB1);
  }

  const int r0 = bm + wr * WTM, c0 = bn + wc * 32;
#pragma unroll
  for (int m = 0; m < MF_M; ++m)
#pragma unroll
    for (int n = 0; n < 2; ++n)
#pragma unroll
      for (int r = 0; r < 4; ++r)
        C[(size_t)(r0 + m * 16 + (lane >> 4) * 4 + r) * N + c0 + n * 16 + (lane & 15)] =
            acc[m][n][r];
}

// ---------------- RMSNorm(q_lat), RMSNorm(c_kv), RoPE(k_rope) ---------------
__global__ __launch_bounds__(256) void rmsnorm_rope(const float* __restrict__ C1,
                                                    const float* __restrict__ qw,
                                                    const float* __restrict__ kvw,
                                                    const float* __restrict__ cosp,
                                                    const float* __restrict__ sinp,
                                                    unsigned short* __restrict__ qn,
                                                    unsigned short* __restrict__ ckvn,
                                                    unsigned short* __restrict__ kr) {
  const int s = blockIdx.x, tid = threadIdx.x;
  const float* row = C1 + (size_t)s * 2048;
  __shared__ float red[4];

  float ss = 0.f;
  for (int c = tid; c < 1024; c += 256) { float v = row[c]; ss += v * v; }
  ss += __shfl_xor(ss, 32); ss += __shfl_xor(ss, 16); ss += __shfl_xor(ss, 8);
  ss += __shfl_xor(ss, 4);  ss += __shfl_xor(ss, 2);  ss += __shfl_xor(ss, 1);
  if ((tid & 63) == 0) red[tid >> 6] = ss;
  __syncthreads();
  float rs = rsqrtf((red[0] + red[1] + red[2] + red[3]) * (1.f / 1024.f) + 1e-6f);
  for (int c = tid; c < 1024; c += 256)
    qn[(size_t)s * 1024 + c] = f2bf(row[c] * rs * qw[c]);

  ss = 0.f;
  for (int c = tid; c < 896; c += 256) { float v = row[1024 + c]; ss += v * v; }
  ss += __shfl_xor(ss, 32); ss += __shfl_xor(ss, 16); ss += __shfl_xor(ss, 8);
  ss += __shfl_xor(ss, 4);  ss += __shfl_xor(ss, 2);  ss += __shfl_xor(ss, 1);
  __syncthreads();
  if ((tid & 63) == 0) red[tid >> 6] = ss;
  __syncthreads();
  rs = rsqrtf((red[0] + red[1] + red[2] + red[3]) * (1.f / 896.f) + 1e-6f);
  for (int c = tid; c < 896; c += 256)
    ckvn[(size_t)s * 896 + c] = f2bf(row[1024 + c] * rs * kvw[c]);

  if (tid < 64) {
    int d = tid;
    float x = row[1920 + d];
    float part = (d < 32) ? -row[1920 + d + 32] : row[1920 + d - 32];
    float v = x * cosp[(size_t)s * 64 + d] + part * sinp[(size_t)s * 64 + d];
    kr[(size_t)s * 64 + d] = f2bf(v);
  }
}

// ---------------- Q post: RoPE + SCALE*log2e -> bf16 ------------------------
// Scale = HD^-0.5 * log2(e) so flash softmax can use exp2 directly.
__global__ __launch_bounds__(256) void q_post(const float* __restrict__ Qf,
                                              const float* __restrict__ cosp,
                                              const float* __restrict__ sinp,
                                              unsigned short* __restrict__ Qb) {
  size_t idx = (size_t)blockIdx.x * 256 + threadIdx.x;
  int s = (int)(idx >> 12);
  int within = (int)(idx & 127);
  float v;
  if (within < 64) {
    v = Qf[idx];
  } else {
    int d = within - 64;
    float x = Qf[idx];
    float part = (d < 32) ? -Qf[idx + 32] : Qf[idx - 32];
    v = x * cosp[(size_t)s * 64 + d] + part * sinp[(size_t)s * 64 + d];
  }
  Qb[idx] = f2bf(v * 0.18033688f);   // 0.125 * log2(e)
}

// ---------------- KV post: Kb=[k_nope|k_rope], Vt = V^T ---------------------
__global__ __launch_bounds__(256) void kv_post(const float* __restrict__ KVf,
                                               const unsigned short* __restrict__ kr,
                                               unsigned short* __restrict__ Kb,
                                               unsigned short* __restrict__ Vt) {
  __shared__ float lT[64 * 65];
  const int s0 = blockIdx.x * 64, h = blockIdx.y, tid = threadIdx.x;
  for (int idx = tid; idx < 4096; idx += 256) {
    int r = idx >> 6, c = idx & 63;
    size_t base = (size_t)(s0 + r) * 4096 + h * 128;
    Kb[base + c] = f2bf(KVf[base + c]);
    Kb[base + 64 + c] = kr[(size_t)(s0 + r) * 64 + c];
    lT[r * 65 + c] = KVf[base + 64 + c];
  }
  __syncthreads();
  for (int idx = tid; idx < 4096; idx += 256) {
    int d = idx >> 6, c = idx & 63;
    Vt[((size_t)h * 64 + d) * 2048 + s0 + c] = f2bf(lT[c * 65 + d]);
  }
}

// ---------------- flash attention (causal, dbuf, exp2 softmax) --------------
// grid (16 qblocks, 32 heads); 512 threads = 8 waves; block = 128 q-rows.
// qb reversed for LPT. K/V double-buffered; 1 barrier per 64-key tile; stage
// for tile t+1 issued before compute(t). LDS XOR-swizzle on lK/lV as in R1.
__global__ __launch_bounds__(512, 4) void flash_attn(const unsigned short* __restrict__ Qb,
                                                     const unsigned short* __restrict__ Kb,
                                                     const unsigned short* __restrict__ Vt,
                                                     unsigned short* __restrict__ Ao) {
  __shared__ unsigned short lK0[64 * 128], lK1[64 * 128];
  __shared__ unsigned short lV0[64 * 64], lV1[64 * 64];
  __shared__ unsigned short lP[128 * 72];
  const int tid = threadIdx.x, lane = tid & 63, wv = tid >> 6;
  const int h = blockIdx.y;
  const int qb = (int)gridDim.x - 1 - (int)blockIdx.x;   // LPT: heavy first
  const int q0 = qb * 128;
  const int nt = 2 * qb + 2;                             // 64-key tiles (even)

  const int firstrow = q0 + wv * 16;
  const int lastrow = firstrow + 15;

  bf16x8 qf[4];
  {
    const unsigned short* qrow = Qb + (size_t)(firstrow + (lane & 15)) * 4096 + h * 128;
#pragma unroll
    for (int ks = 0; ks < 4; ++ks)
      qf[ks] = *reinterpret_cast<const bf16x8*>(qrow + ks * 32 + (lane >> 4) * 8);
  }

  f32x4 o_acc[4] = {};
  float mrow[4] = {-1e30f, -1e30f, -1e30f, -1e30f};
  float lrow[4] = {};

  // staging geometry: K tile 64x128 (1024 chunks, 2/thread), V tile 64x64 (1/thread)
  const int krow = tid >> 4;                          // + i*32
  const int kcol = (((tid & 15) ^ ((tid >> 4) & 7)) * 8);  // swizzled src col
  const int vrow = tid >> 3;
  const int vcol = ((((tid & 7) ^ ((tid >> 3) & 7))) * 8);
  const int swz = lane & 7;                           // read-side row&7

  auto stage = [&](int t, unsigned short* lK, unsigned short* lV) {
    int j0 = t * 64;
#pragma unroll
    for (int i = 0; i < 2; ++i)
      gload_lds16(Kb + (size_t)(j0 + i * 32 + krow) * 4096 + h * 128 + kcol,
                  &lK[(i * 512 + wv * 64) * 8]);
    gload_lds16(Vt + ((size_t)h * 64 + vrow) * 2048 + j0 + vcol, &lV[(wv * 64) * 8]);
  };

  auto compute = [&](int j0, const unsigned short* lK, const unsigned short* lV) {
    if (j0 > lastrow) return;   // past this wave's causal edge

    f32x4 s_acc[4] = {};
    __builtin_amdgcn_s_setprio(1);
#pragma unroll
    for (int n = 0; n < 4; ++n)
#pragma unroll
      for (int ks = 0; ks < 4; ++ks) {
        bf16x8 kf = *reinterpret_cast<const bf16x8*>(
            &lK[(n * 16 + (lane & 15)) * 128 + (((ks * 4 + (lane >> 4)) ^ swz)) * 8]);
        s_acc[n] = __builtin_amdgcn_mfma_f32_16x16x32_bf16(qf[ks], kf, s_acc[n], 0, 0, 0);
      }
    __builtin_amdgcn_s_setprio(0);

    if (j0 + 63 > firstrow) {   // mask window (diagonal region)
#pragma unroll
      for (int n = 0; n < 4; ++n)
#pragma unroll
        for (int r = 0; r < 4; ++r) {
          int qr = firstrow + (lane >> 4) * 4 + r;
          int kc = j0 + n * 16 + (lane & 15);
          if (kc > qr) s_acc[n][r] = -1e30f;
        }
    }

    float mx[4];
#pragma unroll
    for (int r = 0; r < 4; ++r) {
      float m0 = fmaxf(fmaxf(s_acc[0][r], s_acc[1][r]), fmaxf(s_acc[2][r], s_acc[3][r]));
      m0 = fmaxf(m0, __shfl_xor(m0, 1));
      m0 = fmaxf(m0, __shfl_xor(m0, 2));
      m0 = fmaxf(m0, __shfl_xor(m0, 4));
      m0 = fmaxf(m0, __shfl_xor(m0, 8));
      mx[r] = m0;
    }
    // defer-max (T13): rescale only if any row's max grew past THR=8 (exp2 domain)
    float need = fmaxf(fmaxf(mx[0] - mrow[0], mx[1] - mrow[1]),
                       fmaxf(mx[2] - mrow[2], mx[3] - mrow[3]));
    if (__any(need > 8.0f)) {
#pragma unroll
      for (int r = 0; r < 4; ++r) {
        float mn = fmaxf(mrow[r], mx[r]);
        float sf = exp2f(mrow[r] - mn);
        mrow[r] = mn;
        lrow[r] *= sf;
        o_acc[0][r] *= sf; o_acc[1][r] *= sf; o_acc[2][r] *= sf; o_acc[3][r] *= sf;
      }
    }
#pragma unroll
    for (int r = 0; r < 4; ++r) {
      float ps = 0.f;
#pragma unroll
      for (int n = 0; n < 4; ++n) {
        float p = exp2f(s_acc[n][r] - mrow[r]);   // bounded by 2^8
        ps += p;
        lP[(wv * 16 + (lane >> 4) * 4 + r) * 72 + n * 16 + (lane & 15)] = f2bf(p);
      }
      ps += __shfl_xor(ps, 1); ps += __shfl_xor(ps, 2);
      ps += __shfl_xor(ps, 4); ps += __shfl_xor(ps, 8);
      lrow[r] += ps;
    }

    __builtin_amdgcn_s_setprio(1);
#pragma unroll
    for (int ks = 0; ks < 2; ++ks) {
      bf16x8 pa = *reinterpret_cast<const bf16x8*>(
          &lP[(wv * 16 + (lane & 15)) * 72 + ks * 32 + (lane >> 4) * 8]);
#pragma unroll
      for (int n = 0; n < 4; ++n) {
        bf16x8 vb = *reinterpret_cast<const bf16x8*>(
            &lV[(n * 16 + (lane & 15)) * 64 + (((ks * 4 + (lane >> 4)) ^ swz)) * 8]);
        o_acc[n] = __builtin_amdgcn_mfma_f32_16x16x32_bf16(pa, vb, o_acc[n], 0, 0, 0);
      }
    }
    __builtin_amdgcn_s_setprio(0);
  };

  stage(0, lK0, lV0);
  for (int t = 0; t < nt; t += 2) {
    __syncthreads();                         // drain stage(t) into buf0
    stage(t + 1, lK1, lV1);                  // in flight during compute(t)
    compute(t * 64, lK0, lV0);
    __syncthreads();                         // drain stage(t+1); buf0 free
    if (t + 2 < nt) stage(t + 2, lK0, lV0);
    compute((t + 1) * 64, lK1, lV1);
  }

#pragma unroll
  for (int r = 0; r < 4; ++r) {
    float inv = 1.f / lrow[r];
#pragma unroll
    for (int n = 0; n < 4; ++n) {
      float o = o_acc[n][r] * inv;
      Ao[(size_t)(firstrow + (lane >> 4) * 4 + r) * 2048 + h * 64 + n * 16 + (lane & 15)] =
          f2bf(o);
    }
  }
}

// ---------------------------------------------------------------------------
extern "C" void kernel_launch(void* const* d_in, const int* in_sizes, int n_in,
                              void* d_out, int out_size, void* d_ws, size_t ws_size,
                              hipStream_t stream) {
  const float* hs   = (const float*)d_in[0];
  const float* cosp = (const float*)d_in[1];
  const float* sinp = (const float*)d_in[2];
  const float* qaw  = (const float*)d_in[3];
  const float* qaln = (const float*)d_in[4];
  const float* qbwf = (const float*)d_in[5];
  const float* kvaw = (const float*)d_in[6];
  const float* kvln = (const float*)d_in[7];
  const float* kvbwf= (const float*)d_in[8];
  const float* owf  = (const float*)d_in[9];
  float* out = (float*)d_out;
  char* ws = (char*)d_ws;
  const size_t MB = 1u << 20;

  unsigned short* W1b  = (unsigned short*)(ws + 0);        // 8 MB   [dead after gemm1]
  unsigned short* Ao   = (unsigned short*)(ws + 0);        // 8 MB   (flash out)
  unsigned short* qbw  = (unsigned short*)(ws + 8 * MB);   // 8 MB   [dead after gemm2a]
  unsigned short* Vt   = (unsigned short*)(ws + 8 * MB);   // 8 MB   (kv_post out)
  unsigned short* kvbw = (unsigned short*)(ws + 16 * MB);  // 7 MB
  unsigned short* owb  = (unsigned short*)(ws + 23 * MB);  // 8 MB
  unsigned short* hsb  = (unsigned short*)(ws + 31 * MB);  // 8 MB   [dead after gemm1]
  unsigned short* Qb   = (unsigned short*)(ws + 31 * MB);  // 16 MB  (q_post out)
  float*          C1   = (float*)(ws + 39 * MB);           // 16 MB  [dead after rmsnorm]
  unsigned short* Kb   = (unsigned short*)(ws + 47 * MB);  // 16 MB  (kv_post out)
  unsigned short* qln  = (unsigned short*)(ws + 55 * MB);  // 4 MB   [dead after gemm2a]
  unsigned short* ckvn = (unsigned short*)(ws + 59 * MB);  // 3.5 MB [dead after gemm2b]
  unsigned short* kr   = (unsigned short*)(ws + 63 * MB);  // 0.25 MB
  float*          Qf   = (float*)(ws + 64 * MB);           // 32 MB
  float*          KVf  = (float*)(ws + 96 * MB);           // 32 MB
  (void)ws_size; (void)in_sizes; (void)n_in; (void)out_size;

  auto cgrid = [](size_t n) { return dim3((unsigned)((n / 4 + 255) / 256)); };

  cvt_pad<<<cgrid((size_t)1024 * 2048), 256, 0, stream>>>(qaw, W1b, (size_t)1024 * 2048, (size_t)1024 * 2048);
  cvt_pad<<<cgrid((size_t)1024 * 2048), 256, 0, stream>>>(kvaw, W1b + (size_t)1024 * 2048, (size_t)960 * 2048, (size_t)1024 * 2048);
  cvt_pad<<<cgrid((size_t)2048 * 2048), 256, 0, stream>>>(hs, hsb, (size_t)2048 * 2048, (size_t)2048 * 2048);
  cvt_pad<<<cgrid((size_t)4096 * 1024), 256, 0, stream>>>(qbwf, qbw, (size_t)4096 * 1024, (size_t)4096 * 1024);
  cvt_pad<<<cgrid((size_t)4096 * 896), 256, 0, stream>>>(kvbwf, kvbw, (size_t)4096 * 896, (size_t)4096 * 896);
  cvt_pad<<<cgrid((size_t)2048 * 2048), 256, 0, stream>>>(owf, owb, (size_t)2048 * 2048, (size_t)2048 * 2048);

  gemm_bt2<64><<<dim3(32, 16), 512, 0, stream>>>(hsb, W1b, C1, 2048, 2048, 2048);
  rmsnorm_rope<<<2048, 256, 0, stream>>>(C1, qaln, kvln, cosp, sinp, qln, ckvn, kr);
  gemm_bt2<128><<<dim3(32, 16), 512, 0, stream>>>(qln, qbw, Qf, 2048, 4096, 1024);
  gemm_bt2<128><<<dim3(32, 16), 512, 0, stream>>>(ckvn, kvbw, KVf, 2048, 4096, 896);

  q_post<<<dim3((unsigned)(((size_t)2048 * 4096) / 256)), 256, 0, stream>>>(Qf, cosp, sinp, Qb);
  kv_post<<<dim3(32, 32), 256, 0, stream>>>(KVf, kr, Kb, Vt);

  flash_attn<<<dim3(16, 32), 512, 0, stream>>>(Qb, Kb, Vt, Ao);

  gemm_bt2<64><<<dim3(32, 16), 512, 0, stream>>>(Ao, owb, out, 2048, 2048, 2048);
}

// Round 4
// 274.576 us; speedup vs baseline: 1.1355x; 1.1355x over previous
//
#include <hip/hip_runtime.h>

// ---------------------------------------------------------------------------
// MLA (LoraQKV) pipeline for MI355X, bf16 MFMA everywhere.
//   1) cvt_all (segmented converts); 2) gemm C1 = hs@W1^T; 3) rmsnorm_rope;
//   4) gemm Qf/KVf; 5) q_post/kv_post; 6) flash_attn; 7) gemm out = Ao@o_w^T.
// R4: flash reverted to 4-wave/64-row blocks (R2 proven) + K-dbuf (1 barrier
//     per tile) + V-in-registers (global->reg, issued pre-barrier) + exp2
//     softmax + defer-max. GEMMs unified on 128x64 tile (48 KB LDS, 3 blk/CU).
//     Six converts fused into one segmented kernel.
// ---------------------------------------------------------------------------

typedef __attribute__((ext_vector_type(8))) __bf16 bf16x8;
typedef __attribute__((ext_vector_type(4))) float f32x4;

__device__ __forceinline__ unsigned short f2bf(float f) {
  unsigned int x = __builtin_bit_cast(unsigned int, f);
  x += 0x7fffu + ((x >> 16) & 1u);
  return (unsigned short)(x >> 16);
}
__device__ __forceinline__ void gload_lds16(const void* g, void* l) {
  __builtin_amdgcn_global_load_lds(
      (const __attribute__((address_space(1))) void*)g,
      (__attribute__((address_space(3))) void*)l, 16, 0, 0);
}

// ---------------- segmented convert (all f32->bf16 converts in one launch) --
struct CvtSegs {
  const float* src[6];
  unsigned short* dst[6];
  unsigned int n_src[6];
  unsigned int n_tot[6];
  unsigned int blk0[7];   // cumulative block offsets
};

__global__ __launch_bounds__(256) void cvt_all(CvtSegs sg) {
  int b = blockIdx.x;
  int seg = 0;
#pragma unroll
  for (int k = 0; k < 5; ++k)
    if (b >= (int)sg.blk0[k + 1]) seg = k + 1;
  size_t i = ((size_t)(b - sg.blk0[seg]) * 256 + threadIdx.x) * 4;
  if (i >= sg.n_tot[seg]) return;
  unsigned short o0 = 0, o1 = 0, o2 = 0, o3 = 0;
  if (i < sg.n_src[seg]) {
    float4 v = *reinterpret_cast<const float4*>(sg.src[seg] + i);
    o0 = f2bf(v.x); o1 = f2bf(v.y); o2 = f2bf(v.z); o3 = f2bf(v.w);
  }
  *reinterpret_cast<ushort4*>(sg.dst[seg] + i) = make_ushort4(o0, o1, o2, o3);
}

// ---------------- GEMM: C[M,N] = A[M,K] @ B[N,K]^T (bf16 in, f32 out) -------
// 128x64 tile, BK=64, 512 threads (8 waves 4x2, wave tile 32x32), dbuf LDS
// (48 KB -> 3 blocks/CU), 2-phase: stage(t+1) issued before compute(t).
__global__ __launch_bounds__(512, 4) void gemm_bt2(const unsigned short* __restrict__ A,
                                                   const unsigned short* __restrict__ B,
                                                   float* __restrict__ C,
                                                   int M, int N, int K) {
  __shared__ unsigned short lA0[128 * 64], lA1[128 * 64];
  __shared__ unsigned short lB0[64 * 64], lB1[64 * 64];
  const int tid = threadIdx.x, lane = tid & 63, wv = tid >> 6;
  const int wr = wv >> 1, wc = wv & 1;             // 4x2 wave grid
  const int bm = blockIdx.y * 128, bn = blockIdx.x * 64;

  f32x4 acc[2][2] = {};

  const int ar0 = tid >> 3;          // row for chunk c=i*512+tid is i*64+ar0
  const int acol = (tid & 7) * 8;

  auto stage = [&](unsigned short* la, unsigned short* lb, int k0) {
#pragma unroll
    for (int i = 0; i < 2; ++i)
      gload_lds16(A + (size_t)(bm + i * 64 + ar0) * K + k0 + acol,
                  &la[(i * 512 + wv * 64) * 8]);
    gload_lds16(B + (size_t)(bn + ar0) * K + k0 + acol, &lb[(wv * 64) * 8]);
  };

  auto compute = [&](const unsigned short* la, const unsigned short* lb) {
#pragma unroll
    for (int ks = 0; ks < 2; ++ks) {
      bf16x8 af[2], bfr[2];
#pragma unroll
      for (int m = 0; m < 2; ++m)
        af[m] = *reinterpret_cast<const bf16x8*>(
            &la[(wr * 32 + m * 16 + (lane & 15)) * 64 + ks * 32 + (lane >> 4) * 8]);
#pragma unroll
      for (int n = 0; n < 2; ++n)
        bfr[n] = *reinterpret_cast<const bf16x8*>(
            &lb[(wc * 32 + n * 16 + (lane & 15)) * 64 + ks * 32 + (lane >> 4) * 8]);
      __builtin_amdgcn_s_setprio(1);
#pragma unroll
      for (int m = 0; m < 2; ++m)
#pragma unroll
        for (int n = 0; n < 2; ++n)
          acc[m][n] = __builtin_amdgcn_mfma_f32_16x16x32_bf16(af[m], bfr[n], acc[m][n], 0, 0, 0);
      __builtin_amdgcn_s_setprio(0);
    }
  };

  stage(lA0, lB0, 0);
  for (int k0 = 0; k0 < K; k0 += 128) {   // K % 128 == 0 for all call sites
    __syncthreads();                      // stage(k0) -> buf0 ready
    stage(lA1, lB1, k0 + 64);             // in flight during compute(buf0)
    compute(lA0, lB0);
    __syncthreads();                      // buf1 ready; buf0 free
    if (k0 + 128 < K) stage(lA0, lB0, k0 + 128);
    compute(lA1, lB1);
  }

  const int r0 = bm + wr * 32, c0 = bn + wc * 32;
#pragma unroll
  for (int m = 0; m < 2; ++m)
#pragma unroll
    for (int n = 0; n < 2; ++n)
#pragma unroll
      for (int r = 0; r < 4; ++r)
        C[(size_t)(r0 + m * 16 + (lane >> 4) * 4 + r) * N + c0 + n * 16 + (lane & 15)] =
            acc[m][n][r];
}

// ---------------- RMSNorm(q_lat), RMSNorm(c_kv), RoPE(k_rope) ---------------
__global__ __launch_bounds__(256) void rmsnorm_rope(const float* __restrict__ C1,
                                                    const float* __restrict__ qw,
                                                    const float* __restrict__ kvw,
                                                    const float* __restrict__ cosp,
                                                    const float* __restrict__ sinp,
                                                    unsigned short* __restrict__ qn,
                                                    unsigned short* __restrict__ ckvn,
                                                    unsigned short* __restrict__ kr) {
  const int s = blockIdx.x, tid = threadIdx.x;
  const float* row = C1 + (size_t)s * 2048;
  __shared__ float red[4];

  float ss = 0.f;
  for (int c = tid; c < 1024; c += 256) { float v = row[c]; ss += v * v; }
  ss += __shfl_xor(ss, 32); ss += __shfl_xor(ss, 16); ss += __shfl_xor(ss, 8);
  ss += __shfl_xor(ss, 4);  ss += __shfl_xor(ss, 2);  ss += __shfl_xor(ss, 1);
  if ((tid & 63) == 0) red[tid >> 6] = ss;
  __syncthreads();
  float rs = rsqrtf((red[0] + red[1] + red[2] + red[3]) * (1.f / 1024.f) + 1e-6f);
  for (int c = tid; c < 1024; c += 256)
    qn[(size_t)s * 1024 + c] = f2bf(row[c] * rs * qw[c]);

  ss = 0.f;
  for (int c = tid; c < 896; c += 256) { float v = row[1024 + c]; ss += v * v; }
  ss += __shfl_xor(ss, 32); ss += __shfl_xor(ss, 16); ss += __shfl_xor(ss, 8);
  ss += __shfl_xor(ss, 4);  ss += __shfl_xor(ss, 2);  ss += __shfl_xor(ss, 1);
  __syncthreads();
  if ((tid & 63) == 0) red[tid >> 6] = ss;
  __syncthreads();
  rs = rsqrtf((red[0] + red[1] + red[2] + red[3]) * (1.f / 896.f) + 1e-6f);
  for (int c = tid; c < 896; c += 256)
    ckvn[(size_t)s * 896 + c] = f2bf(row[1024 + c] * rs * kvw[c]);

  if (tid < 64) {
    int d = tid;
    float x = row[1920 + d];
    float part = (d < 32) ? -row[1920 + d + 32] : row[1920 + d - 32];
    float v = x * cosp[(size_t)s * 64 + d] + part * sinp[(size_t)s * 64 + d];
    kr[(size_t)s * 64 + d] = f2bf(v);
  }
}

// ---------------- Q post: RoPE + SCALE*log2e -> bf16 ------------------------
__global__ __launch_bounds__(256) void q_post(const float* __restrict__ Qf,
                                              const float* __restrict__ cosp,
                                              const float* __restrict__ sinp,
                                              unsigned short* __restrict__ Qb) {
  size_t idx = (size_t)blockIdx.x * 256 + threadIdx.x;
  int s = (int)(idx >> 12);
  int within = (int)(idx & 127);
  float v;
  if (within < 64) {
    v = Qf[idx];
  } else {
    int d = within - 64;
    float x = Qf[idx];
    float part = (d < 32) ? -Qf[idx + 32] : Qf[idx - 32];
    v = x * cosp[(size_t)s * 64 + d] + part * sinp[(size_t)s * 64 + d];
  }
  Qb[idx] = f2bf(v * 0.18033688f);   // 0.125 * log2(e)
}

// ---------------- KV post: Kb=[k_nope|k_rope], Vt = V^T ---------------------
__global__ __launch_bounds__(256) void kv_post(const float* __restrict__ KVf,
                                               const unsigned short* __restrict__ kr,
                                               unsigned short* __restrict__ Kb,
                                               unsigned short* __restrict__ Vt) {
  __shared__ float lT[64 * 65];
  const int s0 = blockIdx.x * 64, h = blockIdx.y, tid = threadIdx.x;
  for (int idx = tid; idx < 4096; idx += 256) {
    int r = idx >> 6, c = idx & 63;
    size_t base = (size_t)(s0 + r) * 4096 + h * 128;
    Kb[base + c] = f2bf(KVf[base + c]);
    Kb[base + 64 + c] = kr[(size_t)(s0 + r) * 64 + c];
    lT[r * 65 + c] = KVf[base + 64 + c];
  }
  __syncthreads();
  for (int idx = tid; idx < 4096; idx += 256) {
    int d = idx >> 6, c = idx & 63;
    Vt[((size_t)h * 64 + d) * 2048 + s0 + c] = f2bf(lT[c * 65 + d]);
  }
}

// ---------------- flash attention (causal) ----------------------------------
// grid (32 heads, 32 qblocks reversed); 256 threads = 4 waves; 64 q-rows/block.
// K double-buffered in LDS (XOR-swizzled, 1 barrier/tile); V loaded straight
// into registers (issued pre-barrier so HBM/L2 latency hides under QK^T);
// exp2-domain softmax (log2e pre-folded into Q), defer-max THR=8.
__global__ __launch_bounds__(256) void flash_attn(const unsigned short* __restrict__ Qb,
                                                  const unsigned short* __restrict__ Kb,
                                                  const unsigned short* __restrict__ Vt,
                                                  unsigned short* __restrict__ Ao) {
  __shared__ unsigned short lK0[64 * 128], lK1[64 * 128];
  __shared__ unsigned short lP[64 * 72];
  const int tid = threadIdx.x, lane = tid & 63, wv = tid >> 6;
  const int h = blockIdx.x;
  const int qb = (int)gridDim.y - 1 - (int)blockIdx.y;   // LPT: heavy first
  const int q0 = qb * 64;
  const int nt = qb + 1;                                 // 64-key tiles
  const int firstrow = q0 + wv * 16;

  bf16x8 qf[4];
  {
    const unsigned short* qrow = Qb + (size_t)(firstrow + (lane & 15)) * 4096 + h * 128;
#pragma unroll
    for (int ks = 0; ks < 4; ++ks)
      qf[ks] = *reinterpret_cast<const bf16x8*>(qrow + ks * 32 + (lane >> 4) * 8);
  }

  f32x4 o_acc[4] = {};
  float mrow[4] = {-1e30f, -1e30f, -1e30f, -1e30f};
  float lrow[4] = {};

  // K staging geometry: tile 64x128, chunk c = i*256 + tid -> row i*16+wv*4+(lane>>4)
  const int krow = wv * 4 + (lane >> 4);
  const int kcol = (((lane & 15) ^ (krow & 7)) * 8);  // pre-swizzled global col
  const int swz = lane & 7;                           // read-side row&7

  auto stage = [&](int t, unsigned short* lK) {
    int j0 = t * 64;
#pragma unroll
    for (int i = 0; i < 4; ++i)
      gload_lds16(Kb + (size_t)(j0 + i * 16 + krow) * 4096 + h * 128 + kcol,
                  &lK[(i * 16 + wv * 4) * 128]);
  };

  auto loadV = [&](int j0, bf16x8 (&vr)[2][4]) {
#pragma unroll
    for (int ks = 0; ks < 2; ++ks)
#pragma unroll
      for (int n = 0; n < 4; ++n)
        vr[ks][n] = *reinterpret_cast<const bf16x8*>(
            Vt + ((size_t)h * 64 + n * 16 + (lane & 15)) * 2048 + j0 + ks * 32 +
            (lane >> 4) * 8);
  };

  auto computeT = [&](int j0, const unsigned short* lK, const bf16x8 (&vr)[2][4]) {
    f32x4 s_acc[4] = {};
    __builtin_amdgcn_s_setprio(1);
#pragma unroll
    for (int n = 0; n < 4; ++n)
#pragma unroll
      for (int ks = 0; ks < 4; ++ks) {
        bf16x8 kf = *reinterpret_cast<const bf16x8*>(
            &lK[(n * 16 + (lane & 15)) * 128 + (((ks * 4 + (lane >> 4)) ^ swz)) * 8]);
        s_acc[n] = __builtin_amdgcn_mfma_f32_16x16x32_bf16(qf[ks], kf, s_acc[n], 0, 0, 0);
      }
    __builtin_amdgcn_s_setprio(0);

    if (j0 == q0) {  // diagonal tile: causal mask
#pragma unroll
      for (int n = 0; n < 4; ++n)
#pragma unroll
        for (int r = 0; r < 4; ++r) {
          int qr = firstrow + (lane >> 4) * 4 + r;
          int kc = j0 + n * 16 + (lane & 15);
          if (kc > qr) s_acc[n][r] = -1e30f;
        }
    }

    float mx[4];
#pragma unroll
    for (int r = 0; r < 4; ++r) {
      float m0 = fmaxf(fmaxf(s_acc[0][r], s_acc[1][r]), fmaxf(s_acc[2][r], s_acc[3][r]));
      m0 = fmaxf(m0, __shfl_xor(m0, 1));
      m0 = fmaxf(m0, __shfl_xor(m0, 2));
      m0 = fmaxf(m0, __shfl_xor(m0, 4));
      m0 = fmaxf(m0, __shfl_xor(m0, 8));
      mx[r] = m0;
    }
    float need = fmaxf(fmaxf(mx[0] - mrow[0], mx[1] - mrow[1]),
                       fmaxf(mx[2] - mrow[2], mx[3] - mrow[3]));
    if (__any(need > 8.0f)) {   // defer-max (T13), exp2 domain
#pragma unroll
      for (int r = 0; r < 4; ++r) {
        float mn = fmaxf(mrow[r], mx[r]);
        float sf = exp2f(mrow[r] - mn);
        mrow[r] = mn;
        lrow[r] *= sf;
        o_acc[0][r] *= sf; o_acc[1][r] *= sf; o_acc[2][r] *= sf; o_acc[3][r] *= sf;
      }
    }
#pragma unroll
    for (int r = 0; r < 4; ++r) {
      float ps = 0.f;
#pragma unroll
      for (int n = 0; n < 4; ++n) {
        float p = exp2f(s_acc[n][r] - mrow[r]);   // bounded by 2^8
        ps += p;
        lP[(wv * 16 + (lane >> 4) * 4 + r) * 72 + n * 16 + (lane & 15)] = f2bf(p);
      }
      ps += __shfl_xor(ps, 1); ps += __shfl_xor(ps, 2);
      ps += __shfl_xor(ps, 4); ps += __shfl_xor(ps, 8);
      lrow[r] += ps;
    }

    __builtin_amdgcn_s_setprio(1);
#pragma unroll
    for (int ks = 0; ks < 2; ++ks) {
      bf16x8 pa = *reinterpret_cast<const bf16x8*>(
          &lP[(wv * 16 + (lane & 15)) * 72 + ks * 32 + (lane >> 4) * 8]);
#pragma unroll
      for (int n = 0; n < 4; ++n)
        o_acc[n] = __builtin_amdgcn_mfma_f32_16x16x32_bf16(pa, vr[ks][n], o_acc[n], 0, 0, 0);
    }
    __builtin_amdgcn_s_setprio(0);
  };

  bf16x8 vr0[2][4], vr1[2][4];
  stage(0, lK0);
  for (int t = 0; t < nt; t += 2) {
    loadV(t * 64, vr0);                      // pre-barrier: latency overlaps wait
    __syncthreads();                         // lK0(t) ready (vmcnt drained)
    if (t + 1 < nt) stage(t + 1, lK1);       // in flight during compute(t)
    computeT(t * 64, lK0, vr0);
    if (t + 1 < nt) {
      loadV((t + 1) * 64, vr1);
      __syncthreads();                       // lK1 ready; lK0 free
      if (t + 2 < nt) stage(t + 2, lK0);
      computeT((t + 1) * 64, lK1, vr1);
    }
  }

#pragma unroll
  for (int r = 0; r < 4; ++r) {
    float inv = 1.f / lrow[r];
#pragma unroll
    for (int n = 0; n < 4; ++n) {
      float o = o_acc[n][r] * inv;
      Ao[(size_t)(firstrow + (lane >> 4) * 4 + r) * 2048 + h * 64 + n * 16 + (lane & 15)] =
          f2bf(o);
    }
  }
}

// ---------------------------------------------------------------------------
extern "C" void kernel_launch(void* const* d_in, const int* in_sizes, int n_in,
                              void* d_out, int out_size, void* d_ws, size_t ws_size,
                              hipStream_t stream) {
  const float* hs   = (const float*)d_in[0];
  const float* cosp = (const float*)d_in[1];
  const float* sinp = (const float*)d_in[2];
  const float* qaw  = (const float*)d_in[3];
  const float* qaln = (const float*)d_in[4];
  const float* qbwf = (const float*)d_in[5];
  const float* kvaw = (const float*)d_in[6];
  const float* kvln = (const float*)d_in[7];
  const float* kvbwf= (const float*)d_in[8];
  const float* owf  = (const float*)d_in[9];
  float* out = (float*)d_out;
  char* ws = (char*)d_ws;
  const size_t MB = 1u << 20;

  unsigned short* W1b  = (unsigned short*)(ws + 0);        // 8 MB   [dead after gemm1]
  unsigned short* Ao   = (unsigned short*)(ws + 0);        // 8 MB   (flash out)
  unsigned short* qbw  = (unsigned short*)(ws + 8 * MB);   // 8 MB   [dead after gemm2a]
  unsigned short* Vt   = (unsigned short*)(ws + 8 * MB);   // 8 MB   (kv_post out)
  unsigned short* kvbw = (unsigned short*)(ws + 16 * MB);  // 7 MB
  unsigned short* owb  = (unsigned short*)(ws + 23 * MB);  // 8 MB
  unsigned short* hsb  = (unsigned short*)(ws + 31 * MB);  // 8 MB   [dead after gemm1]
  unsigned short* Qb   = (unsigned short*)(ws + 31 * MB);  // 16 MB  (q_post out)
  float*          C1   = (float*)(ws + 39 * MB);           // 16 MB  [dead after rmsnorm]
  unsigned short* Kb   = (unsigned short*)(ws + 47 * MB);  // 16 MB  (kv_post out)
  unsigned short* qln  = (unsigned short*)(ws + 55 * MB);  // 4 MB   [dead after gemm2a]
  unsigned short* ckvn = (unsigned short*)(ws + 59 * MB);  // 3.5 MB [dead after gemm2b]
  unsigned short* kr   = (unsigned short*)(ws + 63 * MB);  // 0.25 MB
  float*          Qf   = (float*)(ws + 64 * MB);           // 32 MB
  float*          KVf  = (float*)(ws + 96 * MB);           // 32 MB
  (void)ws_size; (void)in_sizes; (void)n_in; (void)out_size;

  // ---- one fused convert launch (6 segments) ----
  CvtSegs sg;
  sg.src[0] = qaw;   sg.dst[0] = W1b;                      sg.n_src[0] = 1024u * 2048u; sg.n_tot[0] = 1024u * 2048u;
  sg.src[1] = kvaw;  sg.dst[1] = W1b + (size_t)1024 * 2048; sg.n_src[1] = 960u * 2048u;  sg.n_tot[1] = 1024u * 2048u;
  sg.src[2] = hs;    sg.dst[2] = hsb;                      sg.n_src[2] = 2048u * 2048u; sg.n_tot[2] = 2048u * 2048u;
  sg.src[3] = qbwf;  sg.dst[3] = qbw;                      sg.n_src[3] = 4096u * 1024u; sg.n_tot[3] = 4096u * 1024u;
  sg.src[4] = kvbwf; sg.dst[4] = kvbw;                     sg.n_src[4] = 4096u * 896u;  sg.n_tot[4] = 4096u * 896u;
  sg.src[5] = owf;   sg.dst[5] = owb;                      sg.n_src[5] = 2048u * 2048u; sg.n_tot[5] = 2048u * 2048u;
  sg.blk0[0] = 0;
  for (int k = 0; k < 6; ++k) sg.blk0[k + 1] = sg.blk0[k] + sg.n_tot[k] / 1024u;
  cvt_all<<<dim3(sg.blk0[6]), 256, 0, stream>>>(sg);

  gemm_bt2<<<dim3(32, 16), 512, 0, stream>>>(hsb, W1b, C1, 2048, 2048, 2048);
  rmsnorm_rope<<<2048, 256, 0, stream>>>(C1, qaln, kvln, cosp, sinp, qln, ckvn, kr);
  gemm_bt2<<<dim3(64, 16), 512, 0, stream>>>(qln, qbw, Qf, 2048, 4096, 1024);
  gemm_bt2<<<dim3(64, 16), 512, 0, stream>>>(ckvn, kvbw, KVf, 2048, 4096, 896);

  q_post<<<dim3((unsigned)(((size_t)2048 * 4096) / 256)), 256, 0, stream>>>(Qf, cosp, sinp, Qb);
  kv_post<<<dim3(32, 32), 256, 0, stream>>>(KVf, kr, Kb, Vt);

  flash_attn<<<dim3(32, 32), 256, 0, stream>>>(Qb, Kb, Vt, Ao);

  gemm_bt2<<<dim3(32, 16), 512, 0, stream>>>(Ao, owb, out, 2048, 2048, 2048);
}

// Round 5
// 260.703 us; speedup vs baseline: 1.1960x; 1.0532x over previous
//
#include <hip/hip_runtime.h>

// ---------------------------------------------------------------------------
// MLA (LoraQKV) pipeline for MI355X, bf16 MFMA everywhere.
//   1) cvt_all (segmented converts); 2) gemm C1 = hs@W1^T; 3) rmsnorm_rope;
//   4) gemm Qf/KVf; 5) q_post/kv_post; 6) flash_attn; 7) gemm out = Ao@o_w^T.
// R5: flash softmax made lane-local via SWAPPED QK^T (mfma(K,Q) -> S^T,
//     col=lane&15=q): row reduce = in-reg chain + 2 shfl (was 32 shfl in a
//     4-row serial loop); scalar mrow/lrow; rescale/epilogue cross-lane via
//     4 bpermutes. PV and all loads unchanged. rmsnorm/q_post vectorized x4.
// ---------------------------------------------------------------------------

typedef __attribute__((ext_vector_type(8))) __bf16 bf16x8;
typedef __attribute__((ext_vector_type(4))) float f32x4;

__device__ __forceinline__ unsigned short f2bf(float f) {
  unsigned int x = __builtin_bit_cast(unsigned int, f);
  x += 0x7fffu + ((x >> 16) & 1u);
  return (unsigned short)(x >> 16);
}
__device__ __forceinline__ void gload_lds16(const void* g, void* l) {
  __builtin_amdgcn_global_load_lds(
      (const __attribute__((address_space(1))) void*)g,
      (__attribute__((address_space(3))) void*)l, 16, 0, 0);
}

// ---------------- segmented convert (all f32->bf16 converts in one launch) --
struct CvtSegs {
  const float* src[6];
  unsigned short* dst[6];
  unsigned int n_src[6];
  unsigned int n_tot[6];
  unsigned int blk0[7];
};

__global__ __launch_bounds__(256) void cvt_all(CvtSegs sg) {
  int b = blockIdx.x;
  int seg = 0;
#pragma unroll
  for (int k = 0; k < 5; ++k)
    if (b >= (int)sg.blk0[k + 1]) seg = k + 1;
  size_t i = ((size_t)(b - sg.blk0[seg]) * 256 + threadIdx.x) * 4;
  if (i >= sg.n_tot[seg]) return;
  unsigned short o0 = 0, o1 = 0, o2 = 0, o3 = 0;
  if (i < sg.n_src[seg]) {
    float4 v = *reinterpret_cast<const float4*>(sg.src[seg] + i);
    o0 = f2bf(v.x); o1 = f2bf(v.y); o2 = f2bf(v.z); o3 = f2bf(v.w);
  }
  *reinterpret_cast<ushort4*>(sg.dst[seg] + i) = make_ushort4(o0, o1, o2, o3);
}

// ---------------- GEMM: C[M,N] = A[M,K] @ B[N,K]^T (bf16 in, f32 out) -------
// 128x64 tile, BK=64, 512 threads (8 waves 4x2, wave tile 32x32), dbuf LDS
// (48 KB -> 3 blocks/CU), 2-phase: stage(t+1) issued before compute(t).
__global__ __launch_bounds__(512, 4) void gemm_bt2(const unsigned short* __restrict__ A,
                                                   const unsigned short* __restrict__ B,
                                                   float* __restrict__ C,
                                                   int M, int N, int K) {
  __shared__ unsigned short lA0[128 * 64], lA1[128 * 64];
  __shared__ unsigned short lB0[64 * 64], lB1[64 * 64];
  const int tid = threadIdx.x, lane = tid & 63, wv = tid >> 6;
  const int wr = wv >> 1, wc = wv & 1;             // 4x2 wave grid
  const int bm = blockIdx.y * 128, bn = blockIdx.x * 64;

  f32x4 acc[2][2] = {};

  const int ar0 = tid >> 3;          // row for chunk c=i*512+tid is i*64+ar0
  const int acol = (tid & 7) * 8;

  auto stage = [&](unsigned short* la, unsigned short* lb, int k0) {
#pragma unroll
    for (int i = 0; i < 2; ++i)
      gload_lds16(A + (size_t)(bm + i * 64 + ar0) * K + k0 + acol,
                  &la[(i * 512 + wv * 64) * 8]);
    gload_lds16(B + (size_t)(bn + ar0) * K + k0 + acol, &lb[(wv * 64) * 8]);
  };

  auto compute = [&](const unsigned short* la, const unsigned short* lb) {
#pragma unroll
    for (int ks = 0; ks < 2; ++ks) {
      bf16x8 af[2], bfr[2];
#pragma unroll
      for (int m = 0; m < 2; ++m)
        af[m] = *reinterpret_cast<const bf16x8*>(
            &la[(wr * 32 + m * 16 + (lane & 15)) * 64 + ks * 32 + (lane >> 4) * 8]);
#pragma unroll
      for (int n = 0; n < 2; ++n)
        bfr[n] = *reinterpret_cast<const bf16x8*>(
            &lb[(wc * 32 + n * 16 + (lane & 15)) * 64 + ks * 32 + (lane >> 4) * 8]);
      __builtin_amdgcn_s_setprio(1);
#pragma unroll
      for (int m = 0; m < 2; ++m)
#pragma unroll
        for (int n = 0; n < 2; ++n)
          acc[m][n] = __builtin_amdgcn_mfma_f32_16x16x32_bf16(af[m], bfr[n], acc[m][n], 0, 0, 0);
      __builtin_amdgcn_s_setprio(0);
    }
  };

  stage(lA0, lB0, 0);
  for (int k0 = 0; k0 < K; k0 += 128) {   // K % 128 == 0 for all call sites
    __syncthreads();                      // stage(k0) -> buf0 ready
    stage(lA1, lB1, k0 + 64);             // in flight during compute(buf0)
    compute(lA0, lB0);
    __syncthreads();                      // buf1 ready; buf0 free
    if (k0 + 128 < K) stage(lA0, lB0, k0 + 128);
    compute(lA1, lB1);
  }

  const int r0 = bm + wr * 32, c0 = bn + wc * 32;
#pragma unroll
  for (int m = 0; m < 2; ++m)
#pragma unroll
    for (int n = 0; n < 2; ++n)
#pragma unroll
      for (int r = 0; r < 4; ++r)
        C[(size_t)(r0 + m * 16 + (lane >> 4) * 4 + r) * N + c0 + n * 16 + (lane & 15)] =
            acc[m][n][r];
}

// ---------------- RMSNorm(q_lat), RMSNorm(c_kv), RoPE(k_rope) ---------------
__global__ __launch_bounds__(256) void rmsnorm_rope(const float* __restrict__ C1,
                                                    const float* __restrict__ qw,
                                                    const float* __restrict__ kvw,
                                                    const float* __restrict__ cosp,
                                                    const float* __restrict__ sinp,
                                                    unsigned short* __restrict__ qn,
                                                    unsigned short* __restrict__ ckvn,
                                                    unsigned short* __restrict__ kr) {
  const int s = blockIdx.x, tid = threadIdx.x;
  const float* row = C1 + (size_t)s * 2048;
  __shared__ float red[4];

  // q_lat: 1024 = 256 float4
  float4 v = *reinterpret_cast<const float4*>(row + tid * 4);
  float ss = v.x * v.x + v.y * v.y + v.z * v.z + v.w * v.w;
  ss += __shfl_xor(ss, 32); ss += __shfl_xor(ss, 16); ss += __shfl_xor(ss, 8);
  ss += __shfl_xor(ss, 4);  ss += __shfl_xor(ss, 2);  ss += __shfl_xor(ss, 1);
  if ((tid & 63) == 0) red[tid >> 6] = ss;
  __syncthreads();
  float rs = rsqrtf((red[0] + red[1] + red[2] + red[3]) * (1.f / 1024.f) + 1e-6f);
  {
    float4 w = *reinterpret_cast<const float4*>(qw + tid * 4);
    *reinterpret_cast<ushort4*>(qn + (size_t)s * 1024 + tid * 4) =
        make_ushort4(f2bf(v.x * rs * w.x), f2bf(v.y * rs * w.y),
                     f2bf(v.z * rs * w.z), f2bf(v.w * rs * w.w));
  }

  // c_kv: 896 = 224 float4
  float4 u = make_float4(0.f, 0.f, 0.f, 0.f);
  if (tid < 224) u = *reinterpret_cast<const float4*>(row + 1024 + tid * 4);
  ss = u.x * u.x + u.y * u.y + u.z * u.z + u.w * u.w;
  ss += __shfl_xor(ss, 32); ss += __shfl_xor(ss, 16); ss += __shfl_xor(ss, 8);
  ss += __shfl_xor(ss, 4);  ss += __shfl_xor(ss, 2);  ss += __shfl_xor(ss, 1);
  __syncthreads();
  if ((tid & 63) == 0) red[tid >> 6] = ss;
  __syncthreads();
  rs = rsqrtf((red[0] + red[1] + red[2] + red[3]) * (1.f / 896.f) + 1e-6f);
  if (tid < 224) {
    float4 w = *reinterpret_cast<const float4*>(kvw + tid * 4);
    *reinterpret_cast<ushort4*>(ckvn + (size_t)s * 896 + tid * 4) =
        make_ushort4(f2bf(u.x * rs * w.x), f2bf(u.y * rs * w.y),
                     f2bf(u.z * rs * w.z), f2bf(u.w * rs * w.w));
  }

  if (tid < 64) {
    int d = tid;
    float x = row[1920 + d];
    float part = (d < 32) ? -row[1920 + d + 32] : row[1920 + d - 32];
    float vv = x * cosp[(size_t)s * 64 + d] + part * sinp[(size_t)s * 64 + d];
    kr[(size_t)s * 64 + d] = f2bf(vv);
  }
}

// ---------------- Q post: RoPE + SCALE*log2e -> bf16 (x4 vectorized) --------
__global__ __launch_bounds__(256) void q_post(const float* __restrict__ Qf,
                                              const float* __restrict__ cosp,
                                              const float* __restrict__ sinp,
                                              unsigned short* __restrict__ Qb) {
  size_t base = ((size_t)blockIdx.x * 256 + threadIdx.x) * 4;  // grid covers 2048*4096/4
  int s = (int)(base >> 12);
  int w = (int)(base & 127);   // aligned to 4; 32/64 boundaries preserved
  float4 x = *reinterpret_cast<const float4*>(Qf + base);
  float4 o;
  if (w < 64) {
    o = x;
  } else {
    int d = w - 64;
    float sgn = (d < 32) ? -1.f : 1.f;
    float4 prt = (d < 32) ? *reinterpret_cast<const float4*>(Qf + base + 32)
                          : *reinterpret_cast<const float4*>(Qf + base - 32);
    float4 c = *reinterpret_cast<const float4*>(cosp + (size_t)s * 64 + d);
    float4 sn = *reinterpret_cast<const float4*>(sinp + (size_t)s * 64 + d);
    o.x = x.x * c.x + sgn * prt.x * sn.x;
    o.y = x.y * c.y + sgn * prt.y * sn.y;
    o.z = x.z * c.z + sgn * prt.z * sn.z;
    o.w = x.w * c.w + sgn * prt.w * sn.w;
  }
  const float SC = 0.18033688f;   // 0.125 * log2(e)
  *reinterpret_cast<ushort4*>(Qb + base) =
      make_ushort4(f2bf(o.x * SC), f2bf(o.y * SC), f2bf(o.z * SC), f2bf(o.w * SC));
}

// ---------------- KV post: Kb=[k_nope|k_rope], Vt = V^T ---------------------
__global__ __launch_bounds__(256) void kv_post(const float* __restrict__ KVf,
                                               const unsigned short* __restrict__ kr,
                                               unsigned short* __restrict__ Kb,
                                               unsigned short* __restrict__ Vt) {
  __shared__ float lT[64 * 65];
  const int s0 = blockIdx.x * 64, h = blockIdx.y, tid = threadIdx.x;
  for (int idx = tid; idx < 4096; idx += 256) {
    int r = idx >> 6, c = idx & 63;
    size_t base = (size_t)(s0 + r) * 4096 + h * 128;
    Kb[base + c] = f2bf(KVf[base + c]);
    Kb[base + 64 + c] = kr[(size_t)(s0 + r) * 64 + c];
    lT[r * 65 + c] = KVf[base + 64 + c];
  }
  __syncthreads();
  for (int idx = tid; idx < 4096; idx += 256) {
    int d = idx >> 6, c = idx & 63;
    Vt[((size_t)h * 64 + d) * 2048 + s0 + c] = f2bf(lT[c * 65 + d]);
  }
}

// ---------------- flash attention (causal, swapped QK^T) --------------------
// grid (32 heads, 32 qblocks reversed); 256 threads = 4 waves; 64 q-rows/block.
// QK^T computed as mfma(K, Q) -> S^T with col=lane&15 = q: each lane owns 16
// scores of one q-row -> softmax reduce = in-reg chain + shfl_xor(16,32).
// K dbuf in LDS (XOR-swizzled, 1 barrier/tile); V in registers (pre-barrier);
// exp2-domain (log2e folded into Q), defer-max THR=8.
__global__ __launch_bounds__(256) void flash_attn(const unsigned short* __restrict__ Qb,
                                                  const unsigned short* __restrict__ Kb,
                                                  const unsigned short* __restrict__ Vt,
                                                  unsigned short* __restrict__ Ao) {
  __shared__ unsigned short lK0[64 * 128], lK1[64 * 128];
  __shared__ unsigned short lP[64 * 72];
  const int tid = threadIdx.x, lane = tid & 63, wv = tid >> 6;
  const int h = blockIdx.x;
  const int qb = (int)gridDim.y - 1 - (int)blockIdx.y;   // LPT: heavy first
  const int q0 = qb * 64;
  const int nt = qb + 1;                                 // 64-key tiles
  const int firstrow = q0 + wv * 16;
  const int qa = firstrow + (lane & 15);                 // this lane's q-row

  bf16x8 qf[4];
  {
    const unsigned short* qrow = Qb + (size_t)(firstrow + (lane & 15)) * 4096 + h * 128;
#pragma unroll
    for (int ks = 0; ks < 4; ++ks)
      qf[ks] = *reinterpret_cast<const bf16x8*>(qrow + ks * 32 + (lane >> 4) * 8);
  }

  f32x4 o_acc[4] = {};
  float mrow = -1e30f, lrow = 0.f;   // per-lane: stats of q-row qa

  // K staging geometry: tile 64x128, chunk c = i*256 + tid -> row i*16+wv*4+(lane>>4)
  const int krow = wv * 4 + (lane >> 4);
  const int kcol = (((lane & 15) ^ (krow & 7)) * 8);  // pre-swizzled global col
  const int swz = lane & 7;                           // read-side row&7

  auto stage = [&](int t, unsigned short* lK) {
    int j0 = t * 64;
#pragma unroll
    for (int i = 0; i < 4; ++i)
      gload_lds16(Kb + (size_t)(j0 + i * 16 + krow) * 4096 + h * 128 + kcol,
                  &lK[(i * 16 + wv * 4) * 128]);
  };

  auto loadV = [&](int j0, bf16x8 (&vr)[2][4]) {
#pragma unroll
    for (int ks = 0; ks < 2; ++ks)
#pragma unroll
      for (int n = 0; n < 4; ++n)
        vr[ks][n] = *reinterpret_cast<const bf16x8*>(
            Vt + ((size_t)h * 64 + n * 16 + (lane & 15)) * 2048 + j0 + ks * 32 +
            (lane >> 4) * 8);
  };

  auto computeT = [&](int j0, const unsigned short* lK, const bf16x8 (&vr)[2][4]) {
    f32x4 sT[4] = {};
    // swapped: mfma(K, Q) -> D[key, q]; col=lane&15=q, key=j0+n*16+(lane>>4)*4+r
    __builtin_amdgcn_s_setprio(1);
#pragma unroll
    for (int n = 0; n < 4; ++n)
#pragma unroll
      for (int ks = 0; ks < 4; ++ks) {
        bf16x8 kf = *reinterpret_cast<const bf16x8*>(
            &lK[(n * 16 + (lane & 15)) * 128 + (((ks * 4 + (lane >> 4)) ^ swz)) * 8]);
        sT[n] = __builtin_amdgcn_mfma_f32_16x16x32_bf16(kf, qf[ks], sT[n], 0, 0, 0);
      }
    __builtin_amdgcn_s_setprio(0);

    if (j0 == q0) {  // diagonal tile: causal mask
#pragma unroll
      for (int n = 0; n < 4; ++n)
#pragma unroll
        for (int r = 0; r < 4; ++r) {
          int key = j0 + n * 16 + (lane >> 4) * 4 + r;
          if (key > qa) sT[n][r] = -1e30f;
        }
    }

    // lane-local row max + 2 shfls across the 4 key-groups
    float mx = sT[0][0];
#pragma unroll
    for (int n = 0; n < 4; ++n)
#pragma unroll
      for (int r = 0; r < 4; ++r) mx = fmaxf(mx, sT[n][r]);
    mx = fmaxf(mx, __shfl_xor(mx, 16));
    mx = fmaxf(mx, __shfl_xor(mx, 32));

    if (__any(mx - mrow > 8.0f)) {   // defer-max (T13), exp2 domain
      float mn = fmaxf(mrow, mx);
      float sf = exp2f(mrow - mn);
      mrow = mn;
      lrow *= sf;
      float sfr[4];
#pragma unroll
      for (int r = 0; r < 4; ++r) sfr[r] = __shfl(sf, (lane >> 4) * 4 + r);
#pragma unroll
      for (int n = 0; n < 4; ++n)
#pragma unroll
        for (int r = 0; r < 4; ++r) o_acc[n][r] *= sfr[r];
    }

    float ps = 0.f;
#pragma unroll
    for (int n = 0; n < 4; ++n)
#pragma unroll
      for (int r = 0; r < 4; ++r) {
        float p = exp2f(sT[n][r] - mrow);   // bounded by 2^8
        ps += p;
        lP[(wv * 16 + (lane & 15)) * 72 + n * 16 + (lane >> 4) * 4 + r] = f2bf(p);
      }
    ps += __shfl_xor(ps, 16);
    ps += __shfl_xor(ps, 32);
    lrow += ps;

    __builtin_amdgcn_s_setprio(1);
#pragma unroll
    for (int ks = 0; ks < 2; ++ks) {
      bf16x8 pa = *reinterpret_cast<const bf16x8*>(
          &lP[(wv * 16 + (lane & 15)) * 72 + ks * 32 + (lane >> 4) * 8]);
#pragma unroll
      for (int n = 0; n < 4; ++n)
        o_acc[n] = __builtin_amdgcn_mfma_f32_16x16x32_bf16(pa, vr[ks][n], o_acc[n], 0, 0, 0);
    }
    __builtin_amdgcn_s_setprio(0);
  };

  bf16x8 vr0[2][4], vr1[2][4];
  stage(0, lK0);
  for (int t = 0; t < nt; t += 2) {
    loadV(t * 64, vr0);                      // pre-barrier: latency overlaps wait
    __syncthreads();                         // lK0(t) ready (vmcnt drained)
    if (t + 1 < nt) stage(t + 1, lK1);       // in flight during compute(t)
    computeT(t * 64, lK0, vr0);
    if (t + 1 < nt) {
      loadV((t + 1) * 64, vr1);
      __syncthreads();                       // lK1 ready; lK0 free
      if (t + 2 < nt) stage(t + 2, lK0);
      computeT((t + 1) * 64, lK1, vr1);
    }
  }

  float inv = 1.f / lrow;
  float invr[4];
#pragma unroll
  for (int r = 0; r < 4; ++r) invr[r] = __shfl(inv, (lane >> 4) * 4 + r);
#pragma unroll
  for (int n = 0; n < 4; ++n)
#pragma unroll
    for (int r = 0; r < 4; ++r) {
      float o = o_acc[n][r] * invr[r];
      Ao[(size_t)(firstrow + (lane >> 4) * 4 + r) * 2048 + h * 64 + n * 16 + (lane & 15)] =
          f2bf(o);
    }
}

// ---------------------------------------------------------------------------
extern "C" void kernel_launch(void* const* d_in, const int* in_sizes, int n_in,
                              void* d_out, int out_size, void* d_ws, size_t ws_size,
                              hipStream_t stream) {
  const float* hs   = (const float*)d_in[0];
  const float* cosp = (const float*)d_in[1];
  const float* sinp = (const float*)d_in[2];
  const float* qaw  = (const float*)d_in[3];
  const float* qaln = (const float*)d_in[4];
  const float* qbwf = (const float*)d_in[5];
  const float* kvaw = (const float*)d_in[6];
  const float* kvln = (const float*)d_in[7];
  const float* kvbwf= (const float*)d_in[8];
  const float* owf  = (const float*)d_in[9];
  float* out = (float*)d_out;
  char* ws = (char*)d_ws;
  const size_t MB = 1u << 20;

  unsigned short* W1b  = (unsigned short*)(ws + 0);        // 8 MB   [dead after gemm1]
  unsigned short* Ao   = (unsigned short*)(ws + 0);        // 8 MB   (flash out)
  unsigned short* qbw  = (unsigned short*)(ws + 8 * MB);   // 8 MB   [dead after gemm2a]
  unsigned short* Vt   = (unsigned short*)(ws + 8 * MB);   // 8 MB   (kv_post out)
  unsigned short* kvbw = (unsigned short*)(ws + 16 * MB);  // 7 MB
  unsigned short* owb  = (unsigned short*)(ws + 23 * MB);  // 8 MB
  unsigned short* hsb  = (unsigned short*)(ws + 31 * MB);  // 8 MB   [dead after gemm1]
  unsigned short* Qb   = (unsigned short*)(ws + 31 * MB);  // 16 MB  (q_post out)
  float*          C1   = (float*)(ws + 39 * MB);           // 16 MB  [dead after rmsnorm]
  unsigned short* Kb   = (unsigned short*)(ws + 47 * MB);  // 16 MB  (kv_post out)
  unsigned short* qln  = (unsigned short*)(ws + 55 * MB);  // 4 MB   [dead after gemm2a]
  unsigned short* ckvn = (unsigned short*)(ws + 59 * MB);  // 3.5 MB [dead after gemm2b]
  unsigned short* kr   = (unsigned short*)(ws + 63 * MB);  // 0.25 MB
  float*          Qf   = (float*)(ws + 64 * MB);           // 32 MB
  float*          KVf  = (float*)(ws + 96 * MB);           // 32 MB
  (void)ws_size; (void)in_sizes; (void)n_in; (void)out_size;

  // ---- one fused convert launch (6 segments) ----
  CvtSegs sg;
  sg.src[0] = qaw;   sg.dst[0] = W1b;                      sg.n_src[0] = 1024u * 2048u; sg.n_tot[0] = 1024u * 2048u;
  sg.src[1] = kvaw;  sg.dst[1] = W1b + (size_t)1024 * 2048; sg.n_src[1] = 960u * 2048u;  sg.n_tot[1] = 1024u * 2048u;
  sg.src[2] = hs;    sg.dst[2] = hsb;                      sg.n_src[2] = 2048u * 2048u; sg.n_tot[2] = 2048u * 2048u;
  sg.src[3] = qbwf;  sg.dst[3] = qbw;                      sg.n_src[3] = 4096u * 1024u; sg.n_tot[3] = 4096u * 1024u;
  sg.src[4] = kvbwf; sg.dst[4] = kvbw;                     sg.n_src[4] = 4096u * 896u;  sg.n_tot[4] = 4096u * 896u;
  sg.src[5] = owf;   sg.dst[5] = owb;                      sg.n_src[5] = 2048u * 2048u; sg.n_tot[5] = 2048u * 2048u;
  sg.blk0[0] = 0;
  for (int k = 0; k < 6; ++k) sg.blk0[k + 1] = sg.blk0[k] + sg.n_tot[k] / 1024u;
  cvt_all<<<dim3(sg.blk0[6]), 256, 0, stream>>>(sg);

  gemm_bt2<<<dim3(32, 16), 512, 0, stream>>>(hsb, W1b, C1, 2048, 2048, 2048);
  rmsnorm_rope<<<2048, 256, 0, stream>>>(C1, qaln, kvln, cosp, sinp, qln, ckvn, kr);
  gemm_bt2<<<dim3(64, 16), 512, 0, stream>>>(qln, qbw, Qf, 2048, 4096, 1024);
  gemm_bt2<<<dim3(64, 16), 512, 0, stream>>>(ckvn, kvbw, KVf, 2048, 4096, 896);

  q_post<<<dim3((unsigned)(((size_t)2048 * 4096) / 1024)), 256, 0, stream>>>(Qf, cosp, sinp, Qb);
  kv_post<<<dim3(32, 32), 256, 0, stream>>>(KVf, kr, Kb, Vt);

  flash_attn<<<dim3(32, 32), 256, 0, stream>>>(Qb, Kb, Vt, Ao);

  gemm_bt2<<<dim3(32, 16), 512, 0, stream>>>(Ao, owb, out, 2048, 2048, 2048);
}

// Round 6
// 224.581 us; speedup vs baseline: 1.3883x; 1.1608x over previous
//
#include <hip/hip_runtime.h>

// ---------------------------------------------------------------------------
// MLA (LoraQKV) pipeline for MI355X, bf16 MFMA everywhere.
//   1) cvt_all (segmented converts); 2) gemm C1 = hs@W1^T; 3) rmsnorm_rope;
//   4) gemm Qf/KVf; 5) q_post/kv_post; 6) flash_attn; 7) gemm out = Ao@o_w^T.
// R6: flash P->PV handoff fully in-register (cvt_pk + 16 shfl, lP removed,
//     LDS 32KB -> 4 blocks/CU); GEMM LDS XOR-swizzle via pre-swizzled
//     global_load_lds source + swizzled ds_read chunk (T2).
// ---------------------------------------------------------------------------

typedef __attribute__((ext_vector_type(8))) __bf16 bf16x8;
typedef __attribute__((ext_vector_type(4))) float f32x4;
typedef __attribute__((ext_vector_type(4))) unsigned u32x4;

__device__ __forceinline__ unsigned short f2bf(float f) {
  unsigned int x = __builtin_bit_cast(unsigned int, f);
  x += 0x7fffu + ((x >> 16) & 1u);
  return (unsigned short)(x >> 16);
}
__device__ __forceinline__ void gload_lds16(const void* g, void* l) {
  __builtin_amdgcn_global_load_lds(
      (const __attribute__((address_space(1))) void*)g,
      (__attribute__((address_space(3))) void*)l, 16, 0, 0);
}

// ---------------- segmented convert (all f32->bf16 converts in one launch) --
struct CvtSegs {
  const float* src[6];
  unsigned short* dst[6];
  unsigned int n_src[6];
  unsigned int n_tot[6];
  unsigned int blk0[7];
};

__global__ __launch_bounds__(256) void cvt_all(CvtSegs sg) {
  int b = blockIdx.x;
  int seg = 0;
#pragma unroll
  for (int k = 0; k < 5; ++k)
    if (b >= (int)sg.blk0[k + 1]) seg = k + 1;
  size_t i = ((size_t)(b - sg.blk0[seg]) * 256 + threadIdx.x) * 4;
  if (i >= sg.n_tot[seg]) return;
  unsigned short o0 = 0, o1 = 0, o2 = 0, o3 = 0;
  if (i < sg.n_src[seg]) {
    float4 v = *reinterpret_cast<const float4*>(sg.src[seg] + i);
    o0 = f2bf(v.x); o1 = f2bf(v.y); o2 = f2bf(v.z); o3 = f2bf(v.w);
  }
  *reinterpret_cast<ushort4*>(sg.dst[seg] + i) = make_ushort4(o0, o1, o2, o3);
}

// ---------------- GEMM: C[M,N] = A[M,K] @ B[N,K]^T (bf16 in, f32 out) -------
// 128x64 tile, BK=64, 512 threads (8 waves 4x2, wave tile 32x32), dbuf LDS
// (48 KB -> 3 blocks/CU), 2-phase. T2: LDS XOR-swizzle (chunk ^= row&7) via
// pre-swizzled global source (gload_lds writes linearly) + XOR'd ds_read.
__global__ __launch_bounds__(512, 4) void gemm_bt2(const unsigned short* __restrict__ A,
                                                   const unsigned short* __restrict__ B,
                                                   float* __restrict__ C,
                                                   int M, int N, int K) {
  __shared__ unsigned short lA0[128 * 64], lA1[128 * 64];
  __shared__ unsigned short lB0[64 * 64], lB1[64 * 64];
  const int tid = threadIdx.x, lane = tid & 63, wv = tid >> 6;
  const int wr = wv >> 1, wc = wv & 1;             // 4x2 wave grid
  const int bm = blockIdx.y * 128, bn = blockIdx.x * 64;

  f32x4 acc[2][2] = {};

  const int ar0 = tid >> 3;          // row for chunk c=i*512+tid is i*64+ar0
  // swizzled source column: chunk (tid&7) ^ (row&7); row&7 == (tid>>3)&7 for
  // every load this thread issues (A i=0/1 rows differ by 64, B row = ar0).
  const int acol = (((tid & 7) ^ ((tid >> 3) & 7))) * 8;
  const int swz = lane & 7;          // read-side row&7 (rows are +16-multiples)

  auto stage = [&](unsigned short* la, unsigned short* lb, int k0) {
#pragma unroll
    for (int i = 0; i < 2; ++i)
      gload_lds16(A + (size_t)(bm + i * 64 + ar0) * K + k0 + acol,
                  &la[(i * 512 + wv * 64) * 8]);
    gload_lds16(B + (size_t)(bn + ar0) * K + k0 + acol, &lb[(wv * 64) * 8]);
  };

  auto compute = [&](const unsigned short* la, const unsigned short* lb) {
#pragma unroll
    for (int ks = 0; ks < 2; ++ks) {
      const int ch = ((ks * 4 + (lane >> 4)) ^ swz) * 8;
      bf16x8 af[2], bfr[2];
#pragma unroll
      for (int m = 0; m < 2; ++m)
        af[m] = *reinterpret_cast<const bf16x8*>(
            &la[(wr * 32 + m * 16 + (lane & 15)) * 64 + ch]);
#pragma unroll
      for (int n = 0; n < 2; ++n)
        bfr[n] = *reinterpret_cast<const bf16x8*>(
            &lb[(wc * 32 + n * 16 + (lane & 15)) * 64 + ch]);
      __builtin_amdgcn_s_setprio(1);
#pragma unroll
      for (int m = 0; m < 2; ++m)
#pragma unroll
        for (int n = 0; n < 2; ++n)
          acc[m][n] = __builtin_amdgcn_mfma_f32_16x16x32_bf16(af[m], bfr[n], acc[m][n], 0, 0, 0);
      __builtin_amdgcn_s_setprio(0);
    }
  };

  stage(lA0, lB0, 0);
  for (int k0 = 0; k0 < K; k0 += 128) {   // K % 128 == 0 for all call sites
    __syncthreads();                      // stage(k0) -> buf0 ready
    stage(lA1, lB1, k0 + 64);             // in flight during compute(buf0)
    compute(lA0, lB0);
    __syncthreads();                      // buf1 ready; buf0 free
    if (k0 + 128 < K) stage(lA0, lB0, k0 + 128);
    compute(lA1, lB1);
  }

  const int r0 = bm + wr * 32, c0 = bn + wc * 32;
#pragma unroll
  for (int m = 0; m < 2; ++m)
#pragma unroll
    for (int n = 0; n < 2; ++n)
#pragma unroll
      for (int r = 0; r < 4; ++r)
        C[(size_t)(r0 + m * 16 + (lane >> 4) * 4 + r) * N + c0 + n * 16 + (lane & 15)] =
            acc[m][n][r];
}

// ---------------- RMSNorm(q_lat), RMSNorm(c_kv), RoPE(k_rope) ---------------
__global__ __launch_bounds__(256) void rmsnorm_rope(const float* __restrict__ C1,
                                                    const float* __restrict__ qw,
                                                    const float* __restrict__ kvw,
                                                    const float* __restrict__ cosp,
                                                    const float* __restrict__ sinp,
                                                    unsigned short* __restrict__ qn,
                                                    unsigned short* __restrict__ ckvn,
                                                    unsigned short* __restrict__ kr) {
  const int s = blockIdx.x, tid = threadIdx.x;
  const float* row = C1 + (size_t)s * 2048;
  __shared__ float red[4];

  float4 v = *reinterpret_cast<const float4*>(row + tid * 4);
  float ss = v.x * v.x + v.y * v.y + v.z * v.z + v.w * v.w;
  ss += __shfl_xor(ss, 32); ss += __shfl_xor(ss, 16); ss += __shfl_xor(ss, 8);
  ss += __shfl_xor(ss, 4);  ss += __shfl_xor(ss, 2);  ss += __shfl_xor(ss, 1);
  if ((tid & 63) == 0) red[tid >> 6] = ss;
  __syncthreads();
  float rs = rsqrtf((red[0] + red[1] + red[2] + red[3]) * (1.f / 1024.f) + 1e-6f);
  {
    float4 w = *reinterpret_cast<const float4*>(qw + tid * 4);
    *reinterpret_cast<ushort4*>(qn + (size_t)s * 1024 + tid * 4) =
        make_ushort4(f2bf(v.x * rs * w.x), f2bf(v.y * rs * w.y),
                     f2bf(v.z * rs * w.z), f2bf(v.w * rs * w.w));
  }

  float4 u = make_float4(0.f, 0.f, 0.f, 0.f);
  if (tid < 224) u = *reinterpret_cast<const float4*>(row + 1024 + tid * 4);
  ss = u.x * u.x + u.y * u.y + u.z * u.z + u.w * u.w;
  ss += __shfl_xor(ss, 32); ss += __shfl_xor(ss, 16); ss += __shfl_xor(ss, 8);
  ss += __shfl_xor(ss, 4);  ss += __shfl_xor(ss, 2);  ss += __shfl_xor(ss, 1);
  __syncthreads();
  if ((tid & 63) == 0) red[tid >> 6] = ss;
  __syncthreads();
  rs = rsqrtf((red[0] + red[1] + red[2] + red[3]) * (1.f / 896.f) + 1e-6f);
  if (tid < 224) {
    float4 w = *reinterpret_cast<const float4*>(kvw + tid * 4);
    *reinterpret_cast<ushort4*>(ckvn + (size_t)s * 896 + tid * 4) =
        make_ushort4(f2bf(u.x * rs * w.x), f2bf(u.y * rs * w.y),
                     f2bf(u.z * rs * w.z), f2bf(u.w * rs * w.w));
  }

  if (tid < 64) {
    int d = tid;
    float x = row[1920 + d];
    float part = (d < 32) ? -row[1920 + d + 32] : row[1920 + d - 32];
    float vv = x * cosp[(size_t)s * 64 + d] + part * sinp[(size_t)s * 64 + d];
    kr[(size_t)s * 64 + d] = f2bf(vv);
  }
}

// ---------------- Q post: RoPE + SCALE*log2e -> bf16 (x4 vectorized) --------
__global__ __launch_bounds__(256) void q_post(const float* __restrict__ Qf,
                                              const float* __restrict__ cosp,
                                              const float* __restrict__ sinp,
                                              unsigned short* __restrict__ Qb) {
  size_t base = ((size_t)blockIdx.x * 256 + threadIdx.x) * 4;
  int s = (int)(base >> 12);
  int w = (int)(base & 127);
  float4 x = *reinterpret_cast<const float4*>(Qf + base);
  float4 o;
  if (w < 64) {
    o = x;
  } else {
    int d = w - 64;
    float sgn = (d < 32) ? -1.f : 1.f;
    float4 prt = (d < 32) ? *reinterpret_cast<const float4*>(Qf + base + 32)
                          : *reinterpret_cast<const float4*>(Qf + base - 32);
    float4 c = *reinterpret_cast<const float4*>(cosp + (size_t)s * 64 + d);
    float4 sn = *reinterpret_cast<const float4*>(sinp + (size_t)s * 64 + d);
    o.x = x.x * c.x + sgn * prt.x * sn.x;
    o.y = x.y * c.y + sgn * prt.y * sn.y;
    o.z = x.z * c.z + sgn * prt.z * sn.z;
    o.w = x.w * c.w + sgn * prt.w * sn.w;
  }
  const float SC = 0.18033688f;   // 0.125 * log2(e)
  *reinterpret_cast<ushort4*>(Qb + base) =
      make_ushort4(f2bf(o.x * SC), f2bf(o.y * SC), f2bf(o.z * SC), f2bf(o.w * SC));
}

// ---------------- KV post: Kb=[k_nope|k_rope], Vt = V^T ---------------------
__global__ __launch_bounds__(256) void kv_post(const float* __restrict__ KVf,
                                               const unsigned short* __restrict__ kr,
                                               unsigned short* __restrict__ Kb,
                                               unsigned short* __restrict__ Vt) {
  __shared__ float lT[64 * 65];
  const int s0 = blockIdx.x * 64, h = blockIdx.y, tid = threadIdx.x;
  for (int idx = tid; idx < 4096; idx += 256) {
    int r = idx >> 6, c = idx & 63;
    size_t base = (size_t)(s0 + r) * 4096 + h * 128;
    Kb[base + c] = f2bf(KVf[base + c]);
    Kb[base + 64 + c] = kr[(size_t)(s0 + r) * 64 + c];
    lT[r * 65 + c] = KVf[base + 64 + c];
  }
  __syncthreads();
  for (int idx = tid; idx < 4096; idx += 256) {
    int d = idx >> 6, c = idx & 63;
    Vt[((size_t)h * 64 + d) * 2048 + s0 + c] = f2bf(lT[c * 65 + d]);
  }
}

// ---------------- flash attention (causal, swapped QK^T, in-reg P) ----------
// grid (32 heads, 32 qblocks reversed); 256 threads = 4 waves; 64 q-rows/block.
// QK^T as mfma(K,Q) -> S^T (lane owns one q-row's scores). P->PV A-frag built
// in-register: 8 cvt_pk_bf16 + 16 shfl (derived mapping, no LDS). K dbuf in
// LDS (XOR-swizzled); V in registers (pre-barrier loads); exp2 softmax with
// log2e folded into Q; defer-max THR=8. LDS 32KB -> 4 blocks/CU.
__global__ __launch_bounds__(256, 4) void flash_attn(const unsigned short* __restrict__ Qb,
                                                     const unsigned short* __restrict__ Kb,
                                                     const unsigned short* __restrict__ Vt,
                                                     unsigned short* __restrict__ Ao) {
  __shared__ unsigned short lK0[64 * 128], lK1[64 * 128];
  const int tid = threadIdx.x, lane = tid & 63, wv = tid >> 6;
  const int h = blockIdx.x;
  const int qb = (int)gridDim.y - 1 - (int)blockIdx.y;   // LPT: heavy first
  const int q0 = qb * 64;
  const int nt = qb + 1;                                 // 64-key tiles
  const int firstrow = q0 + wv * 16;
  const int qa = firstrow + (lane & 15);                 // this lane's q-row

  bf16x8 qf[4];
  {
    const unsigned short* qrow = Qb + (size_t)(firstrow + (lane & 15)) * 4096 + h * 128;
#pragma unroll
    for (int ks = 0; ks < 4; ++ks)
      qf[ks] = *reinterpret_cast<const bf16x8*>(qrow + ks * 32 + (lane >> 4) * 8);
  }

  f32x4 o_acc[4] = {};
  float mrow = -1e30f, lrow = 0.f;   // per-lane: stats of q-row qa

  const int g = lane >> 4;
  const int sl0 = ((g & 1) * 2) * 16 + (lane & 15);   // src lane, m=0,1
  const int sl1 = sl0 + 16;                           // src lane, m=2,3
  const bool hi = g >= 2;                             // selects src_n = 2ks+1

  // K staging geometry: tile 64x128, chunk c = i*256 + tid -> row i*16+wv*4+(lane>>4)
  const int krow = wv * 4 + (lane >> 4);
  const int kcol = (((lane & 15) ^ (krow & 7)) * 8);  // pre-swizzled global col
  const int swz = lane & 7;                           // read-side row&7

  auto stage = [&](int t, unsigned short* lK) {
    int j0 = t * 64;
#pragma unroll
    for (int i = 0; i < 4; ++i)
      gload_lds16(Kb + (size_t)(j0 + i * 16 + krow) * 4096 + h * 128 + kcol,
                  &lK[(i * 16 + wv * 4) * 128]);
  };

  auto loadV = [&](int j0, bf16x8 (&vr)[2][4]) {
#pragma unroll
    for (int ks = 0; ks < 2; ++ks)
#pragma unroll
      for (int n = 0; n < 4; ++n)
        vr[ks][n] = *reinterpret_cast<const bf16x8*>(
            Vt + ((size_t)h * 64 + n * 16 + (lane & 15)) * 2048 + j0 + ks * 32 +
            (lane >> 4) * 8);
  };

  auto computeT = [&](int j0, const unsigned short* lK, const bf16x8 (&vr)[2][4]) {
    f32x4 sT[4] = {};
    // swapped: mfma(K, Q) -> D[key, q]; col=lane&15=q, key=j0+n*16+g*4+r
    __builtin_amdgcn_s_setprio(1);
#pragma unroll
    for (int n = 0; n < 4; ++n)
#pragma unroll
      for (int ks = 0; ks < 4; ++ks) {
        bf16x8 kf = *reinterpret_cast<const bf16x8*>(
            &lK[(n * 16 + (lane & 15)) * 128 + (((ks * 4 + (lane >> 4)) ^ swz)) * 8]);
        sT[n] = __builtin_amdgcn_mfma_f32_16x16x32_bf16(kf, qf[ks], sT[n], 0, 0, 0);
      }
    __builtin_amdgcn_s_setprio(0);

    if (j0 == q0) {  // diagonal tile: causal mask
#pragma unroll
      for (int n = 0; n < 4; ++n)
#pragma unroll
        for (int r = 0; r < 4; ++r) {
          int key = j0 + n * 16 + g * 4 + r;
          if (key > qa) sT[n][r] = -1e30f;
        }
    }

    float mx = sT[0][0];
#pragma unroll
    for (int n = 0; n < 4; ++n)
#pragma unroll
      for (int r = 0; r < 4; ++r) mx = fmaxf(mx, sT[n][r]);
    mx = fmaxf(mx, __shfl_xor(mx, 16));
    mx = fmaxf(mx, __shfl_xor(mx, 32));

    if (__any(mx - mrow > 8.0f)) {   // defer-max (T13), exp2 domain
      float mn = fmaxf(mrow, mx);
      float sf = exp2f(mrow - mn);
      mrow = mn;
      lrow *= sf;
      float sfr[4];
#pragma unroll
      for (int r = 0; r < 4; ++r) sfr[r] = __shfl(sf, (lane >> 4) * 4 + r);
#pragma unroll
      for (int n = 0; n < 4; ++n)
#pragma unroll
        for (int r = 0; r < 4; ++r) o_acc[n][r] *= sfr[r];
    }

    // P = exp2(S - m), accumulate l, pack to bf16 pairs in-register.
    float ps = 0.f;
    unsigned dw[4][2];
#pragma unroll
    for (int n = 0; n < 4; ++n) {
      float p0 = exp2f(sT[n][0] - mrow), p1 = exp2f(sT[n][1] - mrow);
      float p2 = exp2f(sT[n][2] - mrow), p3 = exp2f(sT[n][3] - mrow);
      ps += (p0 + p1) + (p2 + p3);
      asm("v_cvt_pk_bf16_f32 %0, %1, %2" : "=v"(dw[n][0]) : "v"(p0), "v"(p1));
      asm("v_cvt_pk_bf16_f32 %0, %1, %2" : "=v"(dw[n][1]) : "v"(p2), "v"(p3));
    }
    ps += __shfl_xor(ps, 16);
    ps += __shfl_xor(ps, 32);
    lrow += ps;

    // A-frag pa[ks] dword m = keys 32ks+8g+2m{,+1} = src lane sl(m>>1),
    // var dw[2ks+(g>>1)][m&1].  (16 shfl + 4 vector selects)
#pragma unroll
    for (int ks = 0; ks < 2; ++ks) {
      unsigned A0 = __shfl(dw[2 * ks][0], sl0);
      unsigned B0 = __shfl(dw[2 * ks + 1][0], sl0);
      unsigned A1 = __shfl(dw[2 * ks][1], sl0);
      unsigned B1 = __shfl(dw[2 * ks + 1][1], sl0);
      unsigned A2 = __shfl(dw[2 * ks][0], sl1);
      unsigned B2 = __shfl(dw[2 * ks + 1][0], sl1);
      unsigned A3 = __shfl(dw[2 * ks][1], sl1);
      unsigned B3 = __shfl(dw[2 * ks + 1][1], sl1);
      u32x4 mm;
      mm.x = hi ? B0 : A0; mm.y = hi ? B1 : A1;
      mm.z = hi ? B2 : A2; mm.w = hi ? B3 : A3;
      bf16x8 pa = __builtin_bit_cast(bf16x8, mm);
      __builtin_amdgcn_s_setprio(1);
#pragma unroll
      for (int n = 0; n < 4; ++n)
        o_acc[n] = __builtin_amdgcn_mfma_f32_16x16x32_bf16(pa, vr[ks][n], o_acc[n], 0, 0, 0);
      __builtin_amdgcn_s_setprio(0);
    }
  };

  bf16x8 vr0[2][4], vr1[2][4];
  stage(0, lK0);
  for (int t = 0; t < nt; t += 2) {
    loadV(t * 64, vr0);                      // pre-barrier: latency overlaps wait
    __syncthreads();                         // lK0(t) ready (vmcnt drained)
    if (t + 1 < nt) stage(t + 1, lK1);       // in flight during compute(t)
    computeT(t * 64, lK0, vr0);
    if (t + 1 < nt) {
      loadV((t + 1) * 64, vr1);
      __syncthreads();                       // lK1 ready; lK0 free
      if (t + 2 < nt) stage(t + 2, lK0);
      computeT((t + 1) * 64, lK1, vr1);
    }
  }

  float inv = 1.f / lrow;
  float invr[4];
#pragma unroll
  for (int r = 0; r < 4; ++r) invr[r] = __shfl(inv, (lane >> 4) * 4 + r);
#pragma unroll
  for (int n = 0; n < 4; ++n)
#pragma unroll
    for (int r = 0; r < 4; ++r) {
      float o = o_acc[n][r] * invr[r];
      Ao[(size_t)(firstrow + (lane >> 4) * 4 + r) * 2048 + h * 64 + n * 16 + (lane & 15)] =
          f2bf(o);
    }
}

// ---------------------------------------------------------------------------
extern "C" void kernel_launch(void* const* d_in, const int* in_sizes, int n_in,
                              void* d_out, int out_size, void* d_ws, size_t ws_size,
                              hipStream_t stream) {
  const float* hs   = (const float*)d_in[0];
  const float* cosp = (const float*)d_in[1];
  const float* sinp = (const float*)d_in[2];
  const float* qaw  = (const float*)d_in[3];
  const float* qaln = (const float*)d_in[4];
  const float* qbwf = (const float*)d_in[5];
  const float* kvaw = (const float*)d_in[6];
  const float* kvln = (const float*)d_in[7];
  const float* kvbwf= (const float*)d_in[8];
  const float* owf  = (const float*)d_in[9];
  float* out = (float*)d_out;
  char* ws = (char*)d_ws;
  const size_t MB = 1u << 20;

  unsigned short* W1b  = (unsigned short*)(ws + 0);        // 8 MB   [dead after gemm1]
  unsigned short* Ao   = (unsigned short*)(ws + 0);        // 8 MB   (flash out)
  unsigned short* qbw  = (unsigned short*)(ws + 8 * MB);   // 8 MB   [dead after gemm2a]
  unsigned short* Vt   = (unsigned short*)(ws + 8 * MB);   // 8 MB   (kv_post out)
  unsigned short* kvbw = (unsigned short*)(ws + 16 * MB);  // 7 MB
  unsigned short* owb  = (unsigned short*)(ws + 23 * MB);  // 8 MB
  unsigned short* hsb  = (unsigned short*)(ws + 31 * MB);  // 8 MB   [dead after gemm1]
  unsigned short* Qb   = (unsigned short*)(ws + 31 * MB);  // 16 MB  (q_post out)
  float*          C1   = (float*)(ws + 39 * MB);           // 16 MB  [dead after rmsnorm]
  unsigned short* Kb   = (unsigned short*)(ws + 47 * MB);  // 16 MB  (kv_post out)
  unsigned short* qln  = (unsigned short*)(ws + 55 * MB);  // 4 MB   [dead after gemm2a]
  unsigned short* ckvn = (unsigned short*)(ws + 59 * MB);  // 3.5 MB [dead after gemm2b]
  unsigned short* kr   = (unsigned short*)(ws + 63 * MB);  // 0.25 MB
  float*          Qf   = (float*)(ws + 64 * MB);           // 32 MB
  float*          KVf  = (float*)(ws + 96 * MB);           // 32 MB
  (void)ws_size; (void)in_sizes; (void)n_in; (void)out_size;

  // ---- one fused convert launch (6 segments) ----
  CvtSegs sg;
  sg.src[0] = qaw;   sg.dst[0] = W1b;                      sg.n_src[0] = 1024u * 2048u; sg.n_tot[0] = 1024u * 2048u;
  sg.src[1] = kvaw;  sg.dst[1] = W1b + (size_t)1024 * 2048; sg.n_src[1] = 960u * 2048u;  sg.n_tot[1] = 1024u * 2048u;
  sg.src[2] = hs;    sg.dst[2] = hsb;                      sg.n_src[2] = 2048u * 2048u; sg.n_tot[2] = 2048u * 2048u;
  sg.src[3] = qbwf;  sg.dst[3] = qbw;                      sg.n_src[3] = 4096u * 1024u; sg.n_tot[3] = 4096u * 1024u;
  sg.src[4] = kvbwf; sg.dst[4] = kvbw;                     sg.n_src[4] = 4096u * 896u;  sg.n_tot[4] = 4096u * 896u;
  sg.src[5] = owf;   sg.dst[5] = owb;                      sg.n_src[5] = 2048u * 2048u; sg.n_tot[5] = 2048u * 2048u;
  sg.blk0[0] = 0;
  for (int k = 0; k < 6; ++k) sg.blk0[k + 1] = sg.blk0[k] + sg.n_tot[k] / 1024u;
  cvt_all<<<dim3(sg.blk0[6]), 256, 0, stream>>>(sg);

  gemm_bt2<<<dim3(32, 16), 512, 0, stream>>>(hsb, W1b, C1, 2048, 2048, 2048);
  rmsnorm_rope<<<2048, 256, 0, stream>>>(C1, qaln, kvln, cosp, sinp, qln, ckvn, kr);
  gemm_bt2<<<dim3(64, 16), 512, 0, stream>>>(qln, qbw, Qf, 2048, 4096, 1024);
  gemm_bt2<<<dim3(64, 16), 512, 0, stream>>>(ckvn, kvbw, KVf, 2048, 4096, 896);

  q_post<<<dim3((unsigned)(((size_t)2048 * 4096) / 1024)), 256, 0, stream>>>(Qf, cosp, sinp, Qb);
  kv_post<<<dim3(32, 32), 256, 0, stream>>>(KVf, kr, Kb, Vt);

  flash_attn<<<dim3(32, 32), 256, 0, stream>>>(Qb, Kb, Vt, Ao);

  gemm_bt2<<<dim3(32, 16), 512, 0, stream>>>(Ao, owb, out, 2048, 2048, 2048);
}